// Round 3
// baseline (568.283 us; speedup 1.0000x reference)
//
#include <hip/hip_runtime.h>

typedef unsigned short ushort_t;
typedef short short8 __attribute__((ext_vector_type(8)));
typedef float f32x4 __attribute__((ext_vector_type(4)));
typedef float f32x16 __attribute__((ext_vector_type(16)));

#define NTOK 4096
#define NCOLS 65536
#define CIN 256

__device__ __forceinline__ float b2f(ushort_t u) {
    union { unsigned int i; float f; } v; v.i = ((unsigned int)u) << 16; return v.f;
}
__device__ __forceinline__ ushort_t f2b(float f) {
    union { float f; unsigned int i; } v; v.f = f;
    unsigned int r = v.i + 0x7FFFu + ((v.i >> 16) & 1u);   // RNE
    return (ushort_t)(r >> 16);
}

// ---------------------------------------------------------------------------
// Convert qkv_w [768*256] and proj_w [256*256] fp32 -> bf16 copies in ws.
__global__ __launch_bounds__(256) void cvt_w(const float* __restrict__ wq,
                                             const float* __restrict__ wp,
                                             ushort_t* __restrict__ wqb,
                                             ushort_t* __restrict__ wpb) {
    int i = blockIdx.x * 256 + threadIdx.x;      // 0 .. 262143
    if (i < 768 * 256) wqb[i] = f2b(wq[i]);
    else               wpb[i - 768 * 256] = f2b(wp[i - 768 * 256]);
}

// ---------------------------------------------------------------------------
// x fp32 [nb][256][4096] (b,c,n) -> XT bf16 [nb*4096][256] (token-major)
// Tier A: grid 256 (all 16 batches).  Tier B: grid 16, x pre-offset to batch.
__global__ __launch_bounds__(256) void transpose_x(const float* __restrict__ x,
                                                   ushort_t* __restrict__ xt) {
    int g = blockIdx.x * 256 + threadIdx.x;      // token index within launch
    int b = g >> 12, n = g & 4095;
    const float* src = x + (size_t)b * (CIN * NTOK) + n;
    ushort_t* dst = xt + (size_t)g * CIN;
    for (int c8 = 0; c8 < CIN / 8; c8++) {
        short8 vr;
#pragma unroll
        for (int j = 0; j < 8; j++)
            vr[j] = (short)f2b(src[(size_t)(c8 * 8 + j) * NTOK]);
        *(short8*)(dst + c8 * 8) = vr;
    }
}

// ---------------------------------------------------------------------------
// C[m][col] = BN( sum_c Wb[m][c] * Xc[col][c] );  Wb/Xc bf16, BN params fp32.
// mode 0: out_b[m*out_stride + (colg-col_off)]                (bf16 qkv)
// mode 1: out_f[(colg>>12)*1048576 + m*4096 + (colg&4095)]    (fp32 d_out, global cols)
// mode 2: out_f[m*4096 + (colg&4095)]                         (fp32, per-batch d_out)
__global__ __launch_bounds__(256) void gemm_bn(const ushort_t* __restrict__ Wb,
                                               const ushort_t* __restrict__ Xc,
                                               const float* __restrict__ gamma,
                                               const float* __restrict__ beta,
                                               const float* __restrict__ mean,
                                               const float* __restrict__ var,
                                               ushort_t* __restrict__ out_b,
                                               float* __restrict__ out_f, int mode,
                                               int col_off, int out_stride) {
    int tid = threadIdx.x;
    int wave = tid >> 6, lane = tid & 63;
    int l15 = lane & 15, q = lane >> 4;    // q in 0..3
    int m0 = blockIdx.y * 64;
    int col0 = col_off + blockIdx.x * 64 + wave * 16;

    f32x4 acc[4];
#pragma unroll
    for (int i = 0; i < 4; i++)
#pragma unroll
        for (int j = 0; j < 4; j++) acc[i][j] = 0.f;

    const ushort_t* bptr = Xc + (size_t)(col0 - col_off + l15) * CIN + q * 8;
    const ushort_t* aptr = Wb + (size_t)(m0 + l15) * CIN + q * 8;

#pragma unroll
    for (int k0 = 0; k0 < CIN; k0 += 32) {
        short8 bf = *(const short8*)(bptr + k0);
#pragma unroll
        for (int mi = 0; mi < 4; mi++) {
            short8 af = *(const short8*)(aptr + (size_t)mi * 16 * CIN + k0);
            acc[mi] = __builtin_amdgcn_mfma_f32_16x16x32_bf16(af, bf, acc[mi], 0, 0, 0);
        }
    }

    int colg = col0 + l15;
#pragma unroll
    for (int mi = 0; mi < 4; mi++) {
#pragma unroll
        for (int r = 0; r < 4; r++) {
            int m = m0 + mi * 16 + q * 4 + r;    // C/D: col=lane&15, row=4*(lane>>4)+reg
            float s = gamma[m] * rsqrtf(var[m] + 1e-5f);
            float sh = beta[m] - mean[m] * s;
            float val = acc[mi][r] * s + sh;
            if (mode == 0) {
                out_b[(size_t)m * out_stride + (colg - col_off)] = f2b(val);
            } else if (mode == 1) {
                int bb = colg >> 12, n = colg & 4095;
                out_f[(size_t)bb * (CIN * NTOK) + (size_t)m * NTOK + n] = val;
            } else {
                out_f[(size_t)m * NTOK + (colg & 4095)] = val;
            }
        }
    }
}

// ---------------------------------------------------------------------------
// attention per (b,h): qkv bf16 rows [768][cstride] -> attT bf16 [token][256]
// Tier A: grid 128, cstride=65536, tok_off=0.  Tier B: grid 8, cstride=4096,
// tok_off=0, qkv/attT pre-offset to the batch.
__global__ __launch_bounds__(256) void attn(const ushort_t* __restrict__ qkv,
                                            size_t cstride, int tok_off,
                                            ushort_t* __restrict__ attT) {
    int bh = blockIdx.x;
    int b = bh >> 3, h = bh & 7;
    int tid = threadIdx.x, wave = tid >> 6, lane = tid & 63;
    int l31 = lane & 31, l5 = lane >> 5;
    size_t bcol = (size_t)b * NTOK;
    int tok_base = tok_off + b * NTOK;

    const ushort_t* qbase = qkv + (size_t)(h * 32) * cstride + bcol;
    const ushort_t* kbase = qkv + (size_t)(256 + h * 32) * cstride + bcol;
    const ushort_t* vbase = qkv + (size_t)(512 + h * 32) * cstride + bcol;

    __shared__ float rowmax[32], rowinv[32];
    __shared__ __align__(16) ushort_t ctxT[32 * 40];
    __shared__ __align__(16) ushort_t obuf[4][32 * 40];
    __shared__ __align__(16) ushort_t ubuf[2 * 32 * 264];
    ushort_t* ldsK = ubuf;                 // [32][264]
    ushort_t* ldsV = ubuf + 32 * 264;      // [32][264]
    float* ctxred = (float*)ubuf;          // [4][1024] (aliases, after K/V use)
    ushort_t* qT = ubuf;                   // [256][40]  (aliases, phase 3)

    // ---- phase 1: q row-softmax stats (rows d = wave + 4i)
    for (int i = 0; i < 8; i++) {
        int d = wave + i * 4;
        const ushort_t* qr = qbase + (size_t)d * cstride;
        float m = -3.4e38f, s = 0.f;
        for (int j = 0; j < 64; j++) {
            float x = b2f(qr[j * 64 + lane]);
            float mn = fmaxf(m, x);
            s = s * __expf(m - mn) + __expf(x - mn);
            m = mn;
        }
        for (int off = 1; off < 64; off <<= 1) {
            float mo = __shfl_xor(m, off);
            float so = __shfl_xor(s, off);
            float mn = fmaxf(m, mo);
            s = s * __expf(m - mn) + so * __expf(mo - mn);
            m = mn;
        }
        if (lane == 0) { rowmax[d] = m; rowinv[d] = 1.f / s; }
    }
    __syncthreads();

    // ---- phase 2: ctx[d][e] = sum_n ksm[d][n] * v[e][n]  (mfma 32x32x16)
    f32x16 ctx;
#pragma unroll
    for (int i = 0; i < 16; i++) ctx[i] = 0.f;

    for (int nc = 0; nc < 16; nc++) {
        int n0 = nc * 256;
        {
            float kv[32];
            float m = -3.4e38f;
#pragma unroll
            for (int d = 0; d < 32; d++) {
                kv[d] = b2f(kbase[(size_t)d * cstride + n0 + tid]);
                m = fmaxf(m, kv[d]);
            }
            float s = 0.f;
#pragma unroll
            for (int d = 0; d < 32; d++) { kv[d] = __expf(kv[d] - m); s += kv[d]; }
            float inv = 1.f / s;
#pragma unroll
            for (int d = 0; d < 32; d++) ldsK[d * 264 + tid] = f2b(kv[d] * inv);
#pragma unroll
            for (int d = 0; d < 32; d++) ldsV[d * 264 + tid] = vbase[(size_t)d * cstride + n0 + tid];
        }
        __syncthreads();
        int tokb = wave * 64;
#pragma unroll
        for (int s4 = 0; s4 < 4; s4++) {
            int tok = tokb + s4 * 16 + l5 * 8;
            short8 af = *(const short8*)(ldsK + l31 * 264 + tok); // A[d][tok]
            short8 bf = *(const short8*)(ldsV + l31 * 264 + tok); // B[tok][e]=v[e][tok]
            ctx = __builtin_amdgcn_mfma_f32_32x32x16_bf16(af, bf, ctx, 0, 0, 0);
        }
        __syncthreads();
    }
#pragma unroll
    for (int r = 0; r < 16; r++) {
        int d = (r & 3) + 8 * (r >> 2) + 4 * l5;  // C/D row (m74/m101 layout)
        ctxred[wave * 1024 + d * 32 + l31] = ctx[r];
    }
    __syncthreads();
    {
        int idx0 = tid * 4;
#pragma unroll
        for (int ii = 0; ii < 4; ii++) {
            int idx = idx0 + ii;
            float s = ctxred[idx] + ctxred[1024 + idx] + ctxred[2048 + idx] + ctxred[3072 + idx];
            int d = idx >> 5, e = idx & 31;
            ctxT[e * 40 + d] = f2b(s);
        }
    }
    __syncthreads();

    // ---- phase 3: out[e][n] = sum_d ctx[d][e] * qsm[d][n]
    short8 a0 = *(const short8*)(ctxT + l31 * 40 + l5 * 8);
    short8 a1 = *(const short8*)(ctxT + l31 * 40 + 16 + l5 * 8);

    for (int nc = 0; nc < 16; nc++) {
        int n0 = nc * 256;
#pragma unroll
        for (int d2 = 0; d2 < 16; d2++) {
            int d0 = d2 * 2;
            float q0 = __expf(b2f(qbase[(size_t)d0 * cstride + n0 + tid]) - rowmax[d0]) * rowinv[d0];
            float q1 = __expf(b2f(qbase[(size_t)(d0 + 1) * cstride + n0 + tid]) - rowmax[d0 + 1]) * rowinv[d0 + 1];
            unsigned int pk = (unsigned int)f2b(q0) | ((unsigned int)f2b(q1) << 16);
            *(unsigned int*)(qT + tid * 40 + d0) = pk;   // qT[tok_local][d]
        }
        __syncthreads();
#pragma unroll
        for (int ti = 0; ti < 2; ti++) {
            int tok0 = (wave + ti * 4) * 32;
            f32x16 acc;
#pragma unroll
            for (int i = 0; i < 16; i++) acc[i] = 0.f;
            short8 b0 = *(const short8*)(qT + (size_t)(tok0 + l31) * 40 + l5 * 8);
            short8 b1 = *(const short8*)(qT + (size_t)(tok0 + l31) * 40 + 16 + l5 * 8);
            acc = __builtin_amdgcn_mfma_f32_32x32x16_bf16(a0, b0, acc, 0, 0, 0);
            acc = __builtin_amdgcn_mfma_f32_32x32x16_bf16(a1, b1, acc, 0, 0, 0);
#pragma unroll
            for (int r = 0; r < 16; r++) {
                int e = (r & 3) + 8 * (r >> 2) + 4 * l5;
                obuf[wave][l31 * 40 + e] = f2b(acc[r]);   // obuf[tok][e]
            }
            __syncthreads();
            {
                int tok = lane >> 1, half = lane & 1;
                const ushort_t* src = &obuf[wave][tok * 40 + half * 16];
                short8 r0 = *(const short8*)src;
                short8 r1 = *(const short8*)(src + 8);
                size_t g = (size_t)(tok_base + n0 + tok0 + tok) * 256 + h * 32 + half * 16;
                *(short8*)(attT + g) = r0;
                *(short8*)(attT + g + 8) = r1;
            }
            __syncthreads();
        }
    }
}

// ---------------------------------------------------------------------------
extern "C" void kernel_launch(void* const* d_in, const int* in_sizes, int n_in,
                              void* d_out, int out_size, void* d_ws, size_t ws_size,
                              hipStream_t stream) {
    const float* x          = (const float*)d_in[0];
    const float* qkv_w      = (const float*)d_in[1];
    const float* qkv_gamma  = (const float*)d_in[2];
    const float* qkv_beta   = (const float*)d_in[3];
    const float* qkv_mean   = (const float*)d_in[4];
    const float* qkv_var    = (const float*)d_in[5];
    const float* proj_w     = (const float*)d_in[6];
    const float* proj_gamma = (const float*)d_in[7];
    const float* proj_beta  = (const float*)d_in[8];
    const float* proj_mean  = (const float*)d_in[9];
    const float* proj_var   = (const float*)d_in[10];

    float* out = (float*)d_out;
    ushort_t* wqb = (ushort_t*)d_ws;                       // 768*256 bf16
    ushort_t* wpb = wqb + 768 * 256;                       // 256*256 bf16
    ushort_t* base = wpb + 256 * 256;                      // ws + 524,288 B

    const size_t TIER_A_NEED = 524288ull + 33554432ull + 100663296ull; // 134,742,016
    cvt_w<<<1024, 256, 0, stream>>>(qkv_w, proj_w, wqb, wpb);

    if (ws_size >= TIER_A_NEED) {
        ushort_t* xt  = base;                              // [65536][256] bf16
        ushort_t* qkv = base + (size_t)NCOLS * CIN;        // [768][65536] bf16
        ushort_t* attT = xt;                               // reuse (xt dead after gemm)
        transpose_x<<<256, 256, 0, stream>>>(x, xt);
        gemm_bn<<<dim3(1024, 12), 256, 0, stream>>>(wqb, xt, qkv_gamma, qkv_beta,
                                                    qkv_mean, qkv_var, qkv, nullptr,
                                                    0, 0, NCOLS);
        attn<<<128, 256, 0, stream>>>(qkv, (size_t)NCOLS, 0, attT);
        gemm_bn<<<dim3(1024, 4), 256, 0, stream>>>(wpb, attT, proj_gamma, proj_beta,
                                                   proj_mean, proj_var, nullptr, out,
                                                   1, 0, 0);
    } else {
        // Tier B: per-batch loop.  xtb 2 MB + qkvb 6.3 MB after the W copies.
        ushort_t* xtb  = base;                             // [4096][256] bf16
        ushort_t* qkvb = base + (size_t)NTOK * CIN;        // [768][4096] bf16
        for (int b = 0; b < 16; b++) {
            const float* xb = x + (size_t)b * (CIN * NTOK);
            transpose_x<<<16, 256, 0, stream>>>(xb, xtb);
            gemm_bn<<<dim3(64, 12), 256, 0, stream>>>(wqb, xtb, qkv_gamma, qkv_beta,
                                                      qkv_mean, qkv_var, qkvb, nullptr,
                                                      0, 0, NTOK);
            attn<<<8, 256, 0, stream>>>(qkvb, (size_t)NTOK, 0, xtb);  // attT = xtb
            gemm_bn<<<dim3(64, 4), 256, 0, stream>>>(wpb, xtb, proj_gamma, proj_beta,
                                                     proj_mean, proj_var, nullptr,
                                                     out + (size_t)b * (CIN * NTOK),
                                                     2, 0, 0);
        }
    }
}

// Round 4
// 305.139 us; speedup vs baseline: 1.8624x; 1.8624x over previous
//
#include <hip/hip_runtime.h>

typedef unsigned short ushort_t;
typedef unsigned int u32;
typedef short short8 __attribute__((ext_vector_type(8)));
typedef float f32x4 __attribute__((ext_vector_type(4)));
typedef float f32x16 __attribute__((ext_vector_type(16)));

#define NTOK 4096
#define NCOLS 65536
#define CIN 256

__device__ __forceinline__ float b2f(ushort_t u) {
    union { unsigned int i; float f; } v; v.i = ((unsigned int)u) << 16; return v.f;
}
__device__ __forceinline__ ushort_t f2b(float f) {
    union { float f; unsigned int i; } v; v.f = f;
    unsigned int r = v.i + 0x7FFFu + ((v.i >> 16) & 1u);   // RNE
    return (ushort_t)(r >> 16);
}

// async global->LDS, 16 B per lane (wave-uniform base + lane*16 semantics)
__device__ __forceinline__ void gl_lds16(const ushort_t* g, ushort_t* l) {
    __builtin_amdgcn_global_load_lds(
        (const __attribute__((address_space(1))) u32*)(const void*)g,
        (__attribute__((address_space(3))) u32*)(void*)l,
        16, 0, 0);
}

// ---------------------------------------------------------------------------
// weights fp32 -> bf16; also zero the 512 KB ctx accumulator (lives in d_out)
__global__ __launch_bounds__(256) void cvt_w(const float* __restrict__ wq,
                                             const float* __restrict__ wp,
                                             ushort_t* __restrict__ wqb,
                                             ushort_t* __restrict__ wpb,
                                             float* __restrict__ ctxz) {
    int i = blockIdx.x * 256 + threadIdx.x;      // 0 .. 262143
    if (i < 768 * 256) wqb[i] = f2b(wq[i]);
    else               wpb[i - 768 * 256] = f2b(wp[i - 768 * 256]);
    if (i < 131072) ctxz[i] = 0.f;
}

// ---------------------------------------------------------------------------
// x fp32 [16][256][4096] -> xt bf16 [65536][256] (token-major)
__global__ __launch_bounds__(256) void transpose_x(const float* __restrict__ x,
                                                   ushort_t* __restrict__ xt) {
    int tl = threadIdx.x & 63, cg = threadIdx.x >> 6;   // 64 tokens x 4 c-groups
    int g = blockIdx.x * 64 + tl;
    int b = g >> 12, n = g & 4095;
    const float* src = x + (size_t)b * (CIN * NTOK) + n;
    ushort_t* dst = xt + (size_t)g * CIN + cg * 64;
    for (int j8 = 0; j8 < 8; j8++) {
        short8 vr;
#pragma unroll
        for (int j = 0; j < 8; j++)
            vr[j] = (short)f2b(src[(size_t)(cg * 64 + j8 * 8 + j) * NTOK]);
        *(short8*)(dst + j8 * 8) = vr;
    }
}

// ---------------------------------------------------------------------------
// m97-style 128x128-tile GEMM + BN epilogue.
// C[m][col] = BN( sum_c W[m][c] * Xc[col][c] ),  W [M][256], Xc [65536][256] bf16
// mode 0: out_b[m*65536 + col] bf16   |   mode 1: out_f[(col>>12)*1M + m*4096 + (col&4095)] fp32
__global__ __launch_bounds__(256) void gemm128(const ushort_t* __restrict__ W,
                                               const ushort_t* __restrict__ Xc,
                                               const float* __restrict__ gamma,
                                               const float* __restrict__ beta,
                                               const float* __restrict__ mean,
                                               const float* __restrict__ var,
                                               ushort_t* __restrict__ out_b,
                                               float* __restrict__ out_f, int mode) {
    __shared__ __align__(16) ushort_t lA[128 * 32];
    __shared__ __align__(16) ushort_t lB[128 * 32];
    int tid = threadIdx.x;
    int wave = tid >> 6, lane = tid & 63;
    int l15 = lane & 15, q = lane >> 4;
    int mh = wave >> 1, nh = wave & 1;
    int m0 = blockIdx.y * 128, colb = blockIdx.x * 128;

    f32x4 acc[4][4];
#pragma unroll
    for (int i = 0; i < 4; i++)
#pragma unroll
        for (int j = 0; j < 4; j++)
#pragma unroll
            for (int r = 0; r < 4; r++) acc[i][j][r] = 0.f;

    // staging: thread t covers row (t>>2) (+64 for round 1), k-bytes (t&3)*16
    const ushort_t* gA0 = W  + (size_t)(m0 +      (tid >> 2)) * CIN + (tid & 3) * 8;
    const ushort_t* gA1 = W  + (size_t)(m0 + 64 + (tid >> 2)) * CIN + (tid & 3) * 8;
    const ushort_t* gB0 = Xc + (size_t)(colb +      (tid >> 2)) * CIN + (tid & 3) * 8;
    const ushort_t* gB1 = Xc + (size_t)(colb + 64 + (tid >> 2)) * CIN + (tid & 3) * 8;
    ushort_t* la0 = &lA[tid * 8];
    ushort_t* la1 = &lA[2048 + tid * 8];
    ushort_t* lb0 = &lB[tid * 8];
    ushort_t* lb1 = &lB[2048 + tid * 8];

    for (int k0 = 0; k0 < CIN; k0 += 32) {
        gl_lds16(gA0 + k0, la0);
        gl_lds16(gA1 + k0, la1);
        gl_lds16(gB0 + k0, lb0);
        gl_lds16(gB1 + k0, lb1);
        __syncthreads();
        short8 af[4], bf[4];
#pragma unroll
        for (int i = 0; i < 4; i++) {
            af[i] = *(const short8*)&lA[(mh * 64 + i * 16 + l15) * 32 + q * 8];
            bf[i] = *(const short8*)&lB[(nh * 64 + i * 16 + l15) * 32 + q * 8];
        }
#pragma unroll
        for (int mi = 0; mi < 4; mi++)
#pragma unroll
            for (int ni = 0; ni < 4; ni++)
                acc[mi][ni] = __builtin_amdgcn_mfma_f32_16x16x32_bf16(af[mi], bf[ni],
                                                                      acc[mi][ni], 0, 0, 0);
        __syncthreads();
    }

    int col_l = colb + nh * 64 + l15;
#pragma unroll
    for (int mi = 0; mi < 4; mi++) {
#pragma unroll
        for (int r = 0; r < 4; r++) {
            int m = m0 + mh * 64 + mi * 16 + q * 4 + r;   // C/D: col=lane&15, row=4*(lane>>4)+reg
            float sc = gamma[m] * rsqrtf(var[m] + 1e-5f);
            float sh = beta[m] - mean[m] * sc;
#pragma unroll
            for (int ni = 0; ni < 4; ni++) {
                float val = acc[mi][ni][r] * sc + sh;
                int col = col_l + ni * 16;
                if (mode == 0) {
                    out_b[(size_t)m * NCOLS + col] = f2b(val);
                } else {
                    int bb = col >> 12, n = col & 4095;
                    out_f[(size_t)bb * (CIN * NTOK) + (size_t)m * NTOK + n] = val;
                }
            }
        }
    }
}

// ---------------------------------------------------------------------------
// In-place softmaxes on the qkv buffer.
// blocks 0..1023   : q rows — softmax over each 4096-token batch segment
// blocks 1024..2047: k      — per-token softmax over the 32 head-dims
__global__ __launch_bounds__(256) void softmax_qk(ushort_t* __restrict__ qkv) {
    int bx = blockIdx.x;
    int tid = threadIdx.x, wave = tid >> 6, lane = tid & 63;
    if (bx < 1024) {
        int rid = bx * 4 + wave;            // 0..4095 = (c,b)
        int c = rid >> 4, b = rid & 15;
        ushort_t* row = qkv + (size_t)c * NCOLS + b * NTOK;
        float v[64];
#pragma unroll
        for (int j = 0; j < 8; j++) {
            short8 pk = *(const short8*)(row + j * 512 + lane * 8);
#pragma unroll
            for (int i = 0; i < 8; i++) v[j * 8 + i] = b2f((ushort_t)pk[i]);
        }
        float m = v[0];
#pragma unroll
        for (int i = 1; i < 64; i++) m = fmaxf(m, v[i]);
        for (int off = 1; off < 64; off <<= 1) m = fmaxf(m, __shfl_xor(m, off));
        float s = 0.f;
#pragma unroll
        for (int i = 0; i < 64; i++) { v[i] = __expf(v[i] - m); s += v[i]; }
        for (int off = 1; off < 64; off <<= 1) s += __shfl_xor(s, off);
        float inv = 1.f / s;
#pragma unroll
        for (int j = 0; j < 8; j++) {
            short8 pk;
#pragma unroll
            for (int i = 0; i < 8; i++) pk[i] = (short)f2b(v[j * 8 + i] * inv);
            *(short8*)(row + j * 512 + lane * 8) = pk;
        }
    } else {
        int idx = bx - 1024;                // 0..1023
        int h = idx >> 7, chunk = idx & 127;
        int col = chunk * 512 + tid * 2;    // 2 tokens per thread
        ushort_t* base = qkv + (size_t)(256 + h * 32) * NCOLS + col;
        float v0[32], v1[32];
#pragma unroll
        for (int d = 0; d < 32; d++) {
            u32 pk = *(const u32*)(base + (size_t)d * NCOLS);
            v0[d] = b2f((ushort_t)(pk & 0xFFFF));
            v1[d] = b2f((ushort_t)(pk >> 16));
        }
        float m0 = v0[0], m1 = v1[0];
#pragma unroll
        for (int d = 1; d < 32; d++) { m0 = fmaxf(m0, v0[d]); m1 = fmaxf(m1, v1[d]); }
        float s0 = 0.f, s1 = 0.f;
#pragma unroll
        for (int d = 0; d < 32; d++) {
            v0[d] = __expf(v0[d] - m0); s0 += v0[d];
            v1[d] = __expf(v1[d] - m1); s1 += v1[d];
        }
        float i0 = 1.f / s0, i1 = 1.f / s1;
#pragma unroll
        for (int d = 0; d < 32; d++) {
            u32 pk = (u32)f2b(v0[d] * i0) | ((u32)f2b(v1[d] * i1) << 16);
            *(u32*)(base + (size_t)d * NCOLS) = pk;
        }
    }
}

// ---------------------------------------------------------------------------
// ctx[bh][d][e] += sum_n ksm[d][n] * v[e][n]   split-K over 8 slices of 512 tokens
__global__ __launch_bounds__(256) void ctx_ker(const ushort_t* __restrict__ qkv,
                                               float* __restrict__ ctxbuf) {
    int s = blockIdx.x, bh = blockIdx.y;
    int b = bh >> 3, h = bh & 7;
    int tid = threadIdx.x, wave = tid >> 6, lane = tid & 63;
    int l31 = lane & 31, l5 = lane >> 5;
    int col0 = b * NTOK + s * 512 + wave * 128;
    const ushort_t* krow = qkv + (size_t)(256 + h * 32 + l31) * NCOLS + col0 + l5 * 8;
    const ushort_t* vrow = qkv + (size_t)(512 + h * 32 + l31) * NCOLS + col0 + l5 * 8;
    f32x16 acc;
#pragma unroll
    for (int i = 0; i < 16; i++) acc[i] = 0.f;
#pragma unroll
    for (int st = 0; st < 8; st++) {
        short8 af = *(const short8*)(krow + st * 16);   // A[d=l31][tok]
        short8 bf = *(const short8*)(vrow + st * 16);   // B[tok][e=l31]
        acc = __builtin_amdgcn_mfma_f32_32x32x16_bf16(af, bf, acc, 0, 0, 0);
    }
    __shared__ float red[4][1024];
#pragma unroll
    for (int r = 0; r < 16; r++) {
        int d = (r & 3) + 8 * (r >> 2) + 4 * l5;        // C/D row (verified m74/m101)
        red[wave][d * 32 + l31] = acc[r];
    }
    __syncthreads();
    int i0 = tid * 4;
#pragma unroll
    for (int i = 0; i < 4; i++) {
        int idx = i0 + i;
        float v = red[0][idx] + red[1][idx] + red[2][idx] + red[3][idx];
        atomicAdd(ctxbuf + (size_t)bh * 1024 + idx, v);
    }
}

// ---------------------------------------------------------------------------
// out[e][n] = sum_d ctx[d][e] * qsm[d][n]  -> attT[token][256], per (bh, 512-token slice)
__global__ __launch_bounds__(256) void out_ker(const ushort_t* __restrict__ qkv,
                                               const float* __restrict__ ctxbuf,
                                               ushort_t* __restrict__ attT) {
    int s = blockIdx.x, bh = blockIdx.y;
    int b = bh >> 3, h = bh & 7;
    int tid = threadIdx.x, wave = tid >> 6, lane = tid & 63;
    int l31 = lane & 31, l5 = lane >> 5;
    __shared__ __align__(16) ushort_t ctxT[32 * 40];
    __shared__ __align__(16) ushort_t qT[256 * 40];
    __shared__ __align__(16) ushort_t obuf[4][32 * 40];

#pragma unroll
    for (int i = 0; i < 4; i++) {
        int idx = tid * 4 + i;
        int d = idx >> 5, e = idx & 31;
        ctxT[e * 40 + d] = f2b(ctxbuf[(size_t)bh * 1024 + idx]);
    }
    __syncthreads();
    short8 a0 = *(const short8*)(ctxT + l31 * 40 + l5 * 8);        // A[e][d 0..15]
    short8 a1 = *(const short8*)(ctxT + l31 * 40 + 16 + l5 * 8);   // A[e][d 16..31]

    const ushort_t* qbase = qkv + (size_t)(h * 32) * NCOLS;
    int segbase = b * NTOK + s * 512;

    for (int nc = 0; nc < 2; nc++) {
        int gcol0 = segbase + nc * 256;
        // stage qsm chunk -> qT[tok][d]  (2-way-bank writes: lanes span d)
        int d = tid & 31, t8 = (tid >> 5) * 8;
#pragma unroll
        for (int jj = 0; jj < 4; jj++) {
            int tok8 = jj * 64 + t8;
            short8 pk = *(const short8*)(qbase + (size_t)d * NCOLS + gcol0 + tok8);
#pragma unroll
            for (int j = 0; j < 8; j++) qT[(tok8 + j) * 40 + d] = (ushort_t)pk[j];
        }
        __syncthreads();
#pragma unroll
        for (int ti = 0; ti < 2; ti++) {
            int tok0 = (wave + ti * 4) * 32;
            f32x16 acc;
#pragma unroll
            for (int i = 0; i < 16; i++) acc[i] = 0.f;
            short8 b0 = *(const short8*)(qT + (size_t)(tok0 + l31) * 40 + l5 * 8);
            short8 b1 = *(const short8*)(qT + (size_t)(tok0 + l31) * 40 + 16 + l5 * 8);
            acc = __builtin_amdgcn_mfma_f32_32x32x16_bf16(a0, b0, acc, 0, 0, 0);
            acc = __builtin_amdgcn_mfma_f32_32x32x16_bf16(a1, b1, acc, 0, 0, 0);
#pragma unroll
            for (int r = 0; r < 16; r++) {
                int e = (r & 3) + 8 * (r >> 2) + 4 * l5;
                obuf[wave][l31 * 40 + e] = f2b(acc[r]);   // obuf[tok][e]
            }
            __syncthreads();
            {
                int tok = lane >> 1, half = lane & 1;
                const ushort_t* srcp = &obuf[wave][tok * 40 + half * 16];
                short8 r0 = *(const short8*)srcp;
                short8 r1 = *(const short8*)(srcp + 8);
                size_t g = (size_t)(gcol0 + tok0 + tok) * 256 + h * 32 + half * 16;
                *(short8*)(attT + g) = r0;
                *(short8*)(attT + g + 8) = r1;
            }
            __syncthreads();
        }
        __syncthreads();   // protect qT before restage
    }
}

// ---------------------------------------------------------------------------
extern "C" void kernel_launch(void* const* d_in, const int* in_sizes, int n_in,
                              void* d_out, int out_size, void* d_ws, size_t ws_size,
                              hipStream_t stream) {
    const float* x          = (const float*)d_in[0];
    const float* qkv_w      = (const float*)d_in[1];
    const float* qkv_gamma  = (const float*)d_in[2];
    const float* qkv_beta   = (const float*)d_in[3];
    const float* qkv_mean   = (const float*)d_in[4];
    const float* qkv_var    = (const float*)d_in[5];
    const float* proj_w     = (const float*)d_in[6];
    const float* proj_gamma = (const float*)d_in[7];
    const float* proj_beta  = (const float*)d_in[8];
    const float* proj_mean  = (const float*)d_in[9];
    const float* proj_var   = (const float*)d_in[10];

    // ws layout (needs exactly 134,742,016 B — proven available in R3)
    ushort_t* wqb = (ushort_t*)d_ws;                 // 393,216 B
    ushort_t* wpb = wqb + 768 * 256;                 // 131,072 B
    ushort_t* xt  = wpb + 256 * 256;                 // @524,288: 33.5 MB
    ushort_t* qkv = xt + (size_t)NCOLS * CIN;        // @34,078,720: 100.7 MB
    float* out    = (float*)d_out;
    float* ctxbuf = (float*)d_out;                   // 512 KB scratch (dead before proj writes)

    cvt_w<<<1024, 256, 0, stream>>>(qkv_w, proj_w, wqb, wpb, ctxbuf);
    transpose_x<<<1024, 256, 0, stream>>>(x, xt);
    gemm128<<<dim3(512, 6), 256, 0, stream>>>(wqb, xt, qkv_gamma, qkv_beta,
                                              qkv_mean, qkv_var, qkv, nullptr, 0);
    softmax_qk<<<2048, 256, 0, stream>>>(qkv);
    ctx_ker<<<dim3(8, 128), 256, 0, stream>>>(qkv, ctxbuf);
    out_ker<<<dim3(8, 128), 256, 0, stream>>>(qkv, ctxbuf, xt);   // attT = xt (dead)
    gemm128<<<dim3(512, 2), 256, 0, stream>>>(wpb, xt, proj_gamma, proj_beta,
                                              proj_mean, proj_var, nullptr, out, 1);
}